// Round 9
// baseline (426.189 us; speedup 1.0000x reference)
//
#include <hip/hip_runtime.h>
#include <hip/hip_cooperative_groups.h>
#include <stdint.h>
#include <math.h>

namespace cg = cooperative_groups;

typedef unsigned short u16;
typedef uint32_t u32;
typedef short bf16x8 __attribute__((ext_vector_type(8)));   // 8 bf16 = 4 VGPRs
typedef float f32x4  __attribute__((ext_vector_type(4)));

#define DEV __device__ __forceinline__

DEV u16 f2bf(float f) {
    union { float f; u32 u; } x; x.f = f;
    u32 lsb = (x.u >> 16) & 1u;
    x.u += 0x7fffu + lsb;            // RNE
    return (u16)(x.u >> 16);
}

// pack two f32 -> two bf16 (round-half-up) in 3 VALU ops
DEV u32 pack2(float a, float b) {
    union { float f; u32 u; } x, y; x.f = a; y.f = b;
    return __builtin_amdgcn_perm(y.u + 0x8000u, x.u + 0x8000u, 0x07060302u);
}

#if __has_builtin(__builtin_amdgcn_exp2f)
DEV float fexp2(float x) { return __builtin_amdgcn_exp2f(x); }
#else
DEV float fexp2(float x) { return __expf(x * 0.69314718056f); }
#endif

DEV f32x4 mfma16(bf16x8 a, bf16x8 b, f32x4 c) {
    return __builtin_amdgcn_mfma_f32_16x16x32_bf16(a, b, c, 0, 0, 0);
}

// ---------------------------------------------------------------------------
// phase 0a: one 64x64 transpose tile: x[b][c][s] f32 -> tok[b][s][c] bf16
// t = LDS scratch, 64x65 u16
// ---------------------------------------------------------------------------
DEV void do_transpose(int id, const float* __restrict__ x, u16* __restrict__ tok,
                      u16* __restrict__ t) {
    const int tid = threadIdx.x;
    const int b = id >> 9, c0 = ((id >> 6) & 7) * 64, s0 = (id & 63) * 64;
    const float* xb = x + ((size_t)b * 512 + c0) * 4096 + s0;
    u16* tb = tok + ((size_t)b * 4096 + s0) * 512 + c0;
    {   // read: 64 rows (c) x 16 float4 cols (s)
        const int jc = tid & 15, i0 = tid >> 4;
#pragma unroll
        for (int ii = 0; ii < 4; ii++) {
            int i = i0 * 4 + ii;
            float4 v = *(const float4*)&xb[(size_t)i * 4096 + jc * 4];
            t[i * 65 + jc * 4 + 0] = f2bf(v.x);
            t[i * 65 + jc * 4 + 1] = f2bf(v.y);
            t[i * 65 + jc * 4 + 2] = f2bf(v.z);
            t[i * 65 + jc * 4 + 3] = f2bf(v.w);
        }
    }
    __syncthreads();
    {   // write: 64 rows (s) x 32 u32 cols (c pairs)
        const int j = tid & 31, i0 = tid >> 5;
#pragma unroll
        for (int ii = 0; ii < 8; ii++) {
            int srow = i0 * 8 + ii;
            u32 v = (u32)t[(j * 2) * 65 + srow] | ((u32)t[(j * 2 + 1) * 65 + srow] << 16);
            *(u32*)(&tb[(size_t)srow * 512 + j * 2]) = v;
        }
    }
}

// phase 0b: one 1024-float chunk of weight conversion (id in [0,1024))
DEV void do_wconv(int id, const float* __restrict__ w0, const float* __restrict__ w1,
                  const float* __restrict__ w2, const float* __restrict__ w3,
                  u16* __restrict__ dst) {
    const int j = id >> 8;
    const float* src = (j == 0) ? w0 : (j == 1) ? w1 : (j == 2) ? w2 : w3;
    int idx = ((id & 255) * 256 + threadIdx.x) * 4;
    float4 v = *(const float4*)&src[idx];
    uint2 pv;
    pv.x = pack2(v.x, v.y);
    pv.y = pack2(v.z, v.w);
    *(uint2*)&dst[(size_t)j * 262144 + idx] = pv;
}

// ---------------------------------------------------------------------------
// Projection GEMM tile (R8 triple-buffered structure, verbatim): 128x128 tile,
// BK=32, 16 K-steps, one barrier per step, prefetch distance 2.
// Ab/Bl: LDS bases, 3 buffers x 4096 u16 each.
// mode 0: out bf16 [b][hd][s][d]  mode 1: out bf16 [b*512+co][s]
// mode 2: out f32 [b*512+co][s]
// ---------------------------------------------------------------------------
DEV void proj_tile(const u16* __restrict__ W, const float* __restrict__ bias,
                   const u16* __restrict__ Bb, void* __restrict__ out,
                   int b, int mode, float scale, int m0, int n0,
                   u16* __restrict__ Ab, u16* __restrict__ Bl) {
    const int tid = threadIdx.x;
    const int wave = tid >> 6, lane = tid & 63, q = lane >> 4, c = lane & 15;

    const int cs = tid & 15, qs = (tid >> 4) & 3, ms = (tid >> 6) & 3;
    const u16* Asrc0 = W  + (size_t)(m0 + ms * 16 + cs) * 512 + qs * 8;
    const u16* Asrc1 = W  + (size_t)(m0 + (ms + 4) * 16 + cs) * 512 + qs * 8;
    const u16* Bsrc0 = Bb + (size_t)(n0 + ms * 16 + cs) * 512 + qs * 8;
    const u16* Bsrc1 = Bb + (size_t)(n0 + (ms + 4) * 16 + cs) * 512 + qs * 8;

    f32x4 acc[4][4] = {};

    // prologue: chunk 0 -> LDS buf 0; chunk 1 held in registers
    int4 pa0 = *(const int4*)&Asrc0[0];
    int4 pa1 = *(const int4*)&Asrc1[0];
    int4 pb0 = *(const int4*)&Bsrc0[0];
    int4 pb1 = *(const int4*)&Bsrc1[0];
    int4 ha0 = *(const int4*)&Asrc0[32];
    int4 ha1 = *(const int4*)&Asrc1[32];
    int4 hb0 = *(const int4*)&Bsrc0[32];
    int4 hb1 = *(const int4*)&Bsrc1[32];
    *(int4*)&Ab[tid * 8]         = pa0;
    *(int4*)&Ab[(tid + 256) * 8] = pa1;
    *(int4*)&Bl[tid * 8]         = pb0;
    *(int4*)&Bl[(tid + 256) * 8] = pb1;
    __syncthreads();

    int p = 0, pw = 1;
    for (int it = 0; it < 16; it++) {
        const int kn = ((it + 2) & 15) * 32;

        int4 na0 = *(const int4*)&Asrc0[kn];
        int4 na1 = *(const int4*)&Asrc1[kn];
        int4 nb0 = *(const int4*)&Bsrc0[kn];
        int4 nb1 = *(const int4*)&Bsrc1[kn];

        bf16x8 af[4], bfr[4];
#pragma unroll
        for (int t = 0; t < 4; t++) {
            int gm = (((wave & 1) * 4 + t) * 4 + q) * 16 + c;
            af[t] = *(const bf16x8*)&Ab[p * 4096 + gm * 8];
            int gn = (((wave >> 1) * 4 + t) * 4 + q) * 16 + c;
            bfr[t] = *(const bf16x8*)&Bl[p * 4096 + gn * 8];
        }
#pragma unroll
        for (int mt = 0; mt < 4; mt++)
#pragma unroll
            for (int nt = 0; nt < 4; nt++)
                acc[mt][nt] = mfma16(af[mt], bfr[nt], acc[mt][nt]);

        *(int4*)&Ab[pw * 4096 + tid * 8]         = ha0;
        *(int4*)&Ab[pw * 4096 + (tid + 256) * 8] = ha1;
        *(int4*)&Bl[pw * 4096 + tid * 8]         = hb0;
        *(int4*)&Bl[pw * 4096 + (tid + 256) * 8] = hb1;
        ha0 = na0; ha1 = na1; hb0 = nb0; hb1 = nb1;
        __syncthreads();
        p = pw; pw = (pw == 2) ? 0 : pw + 1;
    }

    // epilogue: co = mbase+mt*16+q*4+reg ; s = nbase+nt*16+c
    const int mbase = m0 + (wave & 1) * 64, nbase = n0 + (wave >> 1) * 64;
#pragma unroll
    for (int mt = 0; mt < 4; mt++) {
        int co0 = mbase + mt * 16 + q * 4;
        float b0 = bias[co0 + 0], b1 = bias[co0 + 1];
        float b2 = bias[co0 + 2], b3 = bias[co0 + 3];
#pragma unroll
        for (int nt = 0; nt < 4; nt++) {
            int scol = nbase + nt * 16 + c;
            float v0 = (acc[mt][nt][0] + b0) * scale;
            float v1 = (acc[mt][nt][1] + b1) * scale;
            float v2 = (acc[mt][nt][2] + b2) * scale;
            float v3 = (acc[mt][nt][3] + b3) * scale;
            if (mode == 0) {
                uint2 pv; pv.x = pack2(v0, v1); pv.y = pack2(v2, v3);
                size_t idx = ((size_t)(b * 8 + (co0 >> 6)) * 4096 + scol) * 64 + (co0 & 63);
                *(uint2*)&((u16*)out)[idx] = pv;
            } else if (mode == 1) {
                u16* o = (u16*)out;
                o[((size_t)(b * 512 + co0 + 0)) * 4096 + scol] = f2bf(v0);
                o[((size_t)(b * 512 + co0 + 1)) * 4096 + scol] = f2bf(v1);
                o[((size_t)(b * 512 + co0 + 2)) * 4096 + scol] = f2bf(v2);
                o[((size_t)(b * 512 + co0 + 3)) * 4096 + scol] = f2bf(v3);
            } else {
                float* o = (float*)out;
                o[((size_t)(b * 512 + co0 + 0)) * 4096 + scol] = v0;
                o[((size_t)(b * 512 + co0 + 1)) * 4096 + scol] = v1;
                o[((size_t)(b * 512 + co0 + 2)) * 4096 + scol] = v2;
                o[((size_t)(b * 512 + co0 + 3)) * 4096 + scol] = v3;
            }
        }
    }
}

// ---------------------------------------------------------------------------
// Attention tile (R6 validated structure, verbatim): fixed-base softmax,
// double-buffered K/V, one barrier per t-tile, intra-wave P^T shuffle.
// Kl/Vl: 2 x 4096 u16 buffers. Pl: 128 x 72 u16.
// ---------------------------------------------------------------------------
DEV void attn_tile(int s0, int bhd,
                   const u16* __restrict__ Qm, const u16* __restrict__ Km,
                   const u16* __restrict__ Vm, u16* __restrict__ attout,
                   u16* __restrict__ Kl, u16* __restrict__ Vl, u16* __restrict__ Pl) {
    const int tid = threadIdx.x, wave = tid >> 6, lane = tid & 63;
    const int q = lane >> 4, c = lane & 15;
    const u16* Qb = Qm + (size_t)bhd * (4096 * 64);
    const u16* Kb = Km + (size_t)bhd * (4096 * 64);
    const u16* Vb = Vm + (size_t)bhd * (64 * 4096);

    bf16x8 qf[2][2];
#pragma unroll
    for (int st = 0; st < 2; st++)
#pragma unroll
        for (int kd = 0; kd < 2; kd++)
            qf[st][kd] = *(const bf16x8*)
                &Qb[(size_t)(s0 + wave * 32 + st * 16 + c) * 64 + kd * 32 + q * 8];

    const int rr = tid & 15, qq = (tid >> 4) & 3, kk = (tid >> 6) & 1;
    const int t40 = tid >> 7, t41 = t40 + 2;
    const u16* Ksrc0 = Kb + (size_t)(t40 * 16 + rr) * 64 + kk * 32 + qq * 8;
    const u16* Ksrc1 = Kb + (size_t)(t41 * 16 + rr) * 64 + kk * 32 + qq * 8;
    const u16* Vsrc0 = Vb + (size_t)(t40 * 16 + rr) * 4096 + kk * 32 + qq * 8;
    const u16* Vsrc1 = Vb + (size_t)(t41 * 16 + rr) * 4096 + kk * 32 + qq * 8;
    u16* Prow = &Pl[(size_t)(wave * 32 + c) * 72];

    f32x4 oacc[4][2] = {};
    float lsum[2] = {0.f, 0.f};

    *(int4*)&Kl[tid * 8]         = *(const int4*)&Ksrc0[0];
    *(int4*)&Kl[(tid + 256) * 8] = *(const int4*)&Ksrc1[0];
    *(int4*)&Vl[tid * 8]         = *(const int4*)&Vsrc0[0];
    *(int4*)&Vl[(tid + 256) * 8] = *(const int4*)&Vsrc1[0];
    __syncthreads();

    for (int it = 0; it < 64; it++) {
        const int p = it & 1;
        const size_t t0n = (size_t)(((it + 1) & 63) * 64);

        int4 kst0 = *(const int4*)&Ksrc0[t0n * 64];
        int4 kst1 = *(const int4*)&Ksrc1[t0n * 64];
        int4 vst0 = *(const int4*)&Vsrc0[t0n];
        int4 vst1 = *(const int4*)&Vsrc1[t0n];

        f32x4 sacc[4][2] = {};
#pragma unroll
        for (int kd = 0; kd < 2; kd++) {
            bf16x8 ka[4];
#pragma unroll
            for (int tt = 0; tt < 4; tt++)
                ka[tt] = *(const bf16x8*)&Kl[p * 4096 + (((tt * 2 + kd) * 4 + q) * 16 + c) * 8];
#pragma unroll
            for (int tt = 0; tt < 4; tt++)
#pragma unroll
                for (int st = 0; st < 2; st++)
                    sacc[tt][st] = mfma16(ka[tt], qf[st][kd], sacc[tt][st]);
        }

#pragma unroll
        for (int st = 0; st < 2; st++) {
#pragma unroll
            for (int tt = 0; tt < 4; tt++) {
                float p0 = fexp2(sacc[tt][st][0]);
                float p1 = fexp2(sacc[tt][st][1]);
                float p2 = fexp2(sacc[tt][st][2]);
                float p3 = fexp2(sacc[tt][st][3]);
                lsum[st] += (p0 + p1) + (p2 + p3);
                uint2 pv; pv.x = pack2(p0, p1); pv.y = pack2(p2, p3);
                *(uint2*)&Prow[st * (16 * 72) + tt * 16 + q * 4] = pv;
            }
        }

#pragma unroll
        for (int kt = 0; kt < 2; kt++) {
            bf16x8 va[4], pb[2];
#pragma unroll
            for (int dt = 0; dt < 4; dt++)
                va[dt] = *(const bf16x8*)&Vl[p * 4096 + (((dt * 2 + kt) * 4 + q) * 16 + c) * 8];
#pragma unroll
            for (int st = 0; st < 2; st++)
                pb[st] = *(const bf16x8*)&Prow[st * (16 * 72) + kt * 32 + q * 8];
#pragma unroll
            for (int dt = 0; dt < 4; dt++)
#pragma unroll
                for (int st = 0; st < 2; st++)
                    oacc[dt][st] = mfma16(va[dt], pb[st], oacc[dt][st]);
        }

        *(int4*)&Kl[(1 - p) * 4096 + tid * 8]         = kst0;
        *(int4*)&Kl[(1 - p) * 4096 + (tid + 256) * 8] = kst1;
        *(int4*)&Vl[(1 - p) * 4096 + tid * 8]         = vst0;
        *(int4*)&Vl[(1 - p) * 4096 + (tid + 256) * 8] = vst1;
        __syncthreads();
    }

    const int b = bhd >> 3, hd = bhd & 7;
#pragma unroll
    for (int st = 0; st < 2; st++) {
        float l = lsum[st];
        l += __shfl_xor(l, 16, 64);
        l += __shfl_xor(l, 32, 64);
        float rl = 1.0f / l;
        int s = s0 + wave * 32 + st * 16 + c;
#pragma unroll
        for (int dt = 0; dt < 4; dt++) {
            uint2 pv;
            pv.x = pack2(oacc[dt][st][0] * rl, oacc[dt][st][1] * rl);
            pv.y = pack2(oacc[dt][st][2] * rl, oacc[dt][st][3] * rl);
            size_t idx = ((size_t)(b * 4096 + s)) * 512 + hd * 64 + dt * 16 + q * 4;
            *(uint2*)&attout[idx] = pv;
        }
    }
}

// ---------------------------------------------------------------------------
// Fused pipeline. coop=1 (cooperative, phase=-1): one launch, grid syncs
// between phases. coop=0: launched once per phase (R8-equivalent fallback).
// Grid (coop): 512 WGs x 256 thr, 2 WGs/CU co-resident (LDS 50KB).
// ---------------------------------------------------------------------------
__global__ __launch_bounds__(256) void fused_kernel(
    int phase, int coop,
    const float* __restrict__ x,
    const float* __restrict__ Wq, const float* __restrict__ bq,
    const float* __restrict__ Wk, const float* __restrict__ bk,
    const float* __restrict__ Wv, const float* __restrict__ bv,
    const float* __restrict__ Wp, const float* __restrict__ bp,
    u16* __restrict__ tok, u16* __restrict__ Qb, u16* __restrict__ Kb,
    u16* __restrict__ Vb, u16* __restrict__ Wbf, u16* __restrict__ attout,
    float* __restrict__ out) {
    __shared__ __align__(16) u16 sm[25600];   // 51200 B union across phases
    const int wg = blockIdx.x;

    if (phase <= 0) {   // phase 0: prep (2 transpose tiles + 2 w-conv chunks)
        do_transpose(wg, x, tok, sm);
        __syncthreads();
        do_transpose(wg + 512, x, tok, sm);
        do_wconv(wg, Wq, Wk, Wv, Wp, Wbf);
        do_wconv(wg + 512, Wq, Wk, Wv, Wp, Wbf);
    }
    if (coop) cg::this_grid().sync();

    if (phase == -1 || phase == 1) {   // phase 1: QKV (768 jobs)
        int job = wg;
        for (;;) {
            int pb = job >> 7, t = job & 127;
            int j = pb >> 1, b = pb & 1;
            int m0 = (t >> 5) * 128, n0 = (t & 31) * 128;
            const u16* W = Wbf + (size_t)j * 262144;
            const float* bias = (j == 0) ? bq : (j == 1) ? bk : bv;
            void* o = (j == 0) ? (void*)Qb : (j == 1) ? (void*)Kb : (void*)Vb;
            float scale = (j == 0) ? 0.1803368801f : 1.0f;   // log2(e)/8
            int mode = (j == 2) ? 1 : 0;
            proj_tile(W, bias, tok + (size_t)b * (4096 * 512), o, b, mode, scale,
                      m0, n0, sm, sm + 12288);
            if (phase == -1 && wg < 256 && job == wg) { job = wg + 512; continue; }
            break;
        }
    }
    if (coop) cg::this_grid().sync();

    if (phase == -1 || phase == 2) {   // phase 2: attention (512 jobs)
        attn_tile((wg & 31) * 128, wg >> 5, Qb, Kb, Vb, attout,
                  sm, sm + 8192, sm + 16384);
    }
    if (coop) cg::this_grid().sync();

    if ((phase == -1 && wg < 256) || phase == 3) {   // phase 3: out-proj (256 jobs)
        int b = wg >> 7, t = wg & 127;
        int m0 = (t >> 5) * 128, n0 = (t & 31) * 128;
        proj_tile(Wbf + (size_t)3 * 262144, bp, attout + (size_t)b * (4096 * 512),
                  out, b, 2, 1.0f, m0, n0, sm, sm + 12288);
    }
}

// ---------------------------------------------------------------------------
extern "C" void kernel_launch(void* const* d_in, const int* in_sizes, int n_in,
                              void* d_out, int out_size, void* d_ws, size_t ws_size,
                              hipStream_t stream) {
    (void)in_sizes; (void)n_in; (void)out_size; (void)ws_size;
    const float* x  = (const float*)d_in[0];
    const float* Wq = (const float*)d_in[1];
    const float* bq = (const float*)d_in[2];
    const float* Wk = (const float*)d_in[3];
    const float* bk = (const float*)d_in[4];
    const float* Wv = (const float*)d_in[5];
    const float* bv = (const float*)d_in[6];
    const float* Wp = (const float*)d_in[7];
    const float* bp = (const float*)d_in[8];
    float* out = (float*)d_out;

    const size_t NTOK = (size_t)4 * 1024 * 1024;  // 2*4096*512 elements
    u16* tok = (u16*)d_ws;        // [2][4096][512] bf16; reused as attout later
    u16* Qb  = tok + NTOK;        // [16][4096][64]  (pre-scaled by log2e/8)
    u16* Kb  = Qb + NTOK;         // [16][4096][64]
    u16* Vb  = Kb + NTOK;         // [16][64][4096]
    u16* Wbf = Vb + NTOK;         // [4][512][512] bf16 (q,k,v,p)
    u16* attout = tok;            // alias: tok dead after V projection

    int phase = -1, coop = 1;
    void* args[] = {&phase, &coop, &x, &Wq, &bq, &Wk, &bk, &Wv, &bv, &Wp, &bp,
                    &tok, &Qb, &Kb, &Vb, &Wbf, &attout, &out};
    hipError_t e = hipLaunchCooperativeKernel((const void*)fused_kernel,
                                              dim3(512), dim3(256), args, 0, stream);
    if (e != hipSuccess) {
        (void)hipGetLastError();   // clear; fall back to 4 phase launches (R8-equivalent)
        fused_kernel<<<512, 256, 0, stream>>>(0, 0, x, Wq, bq, Wk, bk, Wv, bv, Wp, bp,
                                              tok, Qb, Kb, Vb, Wbf, attout, out);
        fused_kernel<<<768, 256, 0, stream>>>(1, 0, x, Wq, bq, Wk, bk, Wv, bv, Wp, bp,
                                              tok, Qb, Kb, Vb, Wbf, attout, out);
        fused_kernel<<<512, 256, 0, stream>>>(2, 0, x, Wq, bq, Wk, bk, Wv, bv, Wp, bp,
                                              tok, Qb, Kb, Vb, Wbf, attout, out);
        fused_kernel<<<256, 256, 0, stream>>>(3, 0, x, Wq, bq, Wk, bk, Wv, bv, Wp, bp,
                                              tok, Qb, Kb, Vb, Wbf, attout, out);
    }
}

// Round 10
// 249.126 us; speedup vs baseline: 1.7107x; 1.7107x over previous
//
#include <hip/hip_runtime.h>
#include <stdint.h>
#include <math.h>

typedef unsigned short u16;
typedef uint32_t u32;
typedef short bf16x8 __attribute__((ext_vector_type(8)));   // 8 bf16 = 4 VGPRs
typedef float f32x4  __attribute__((ext_vector_type(4)));

#define DEV __device__ __forceinline__

DEV u16 f2bf(float f) {
    union { float f; u32 u; } x; x.f = f;
    u32 lsb = (x.u >> 16) & 1u;
    x.u += 0x7fffu + lsb;            // RNE
    return (u16)(x.u >> 16);
}

// pack two f32 -> two bf16 (round-half-up) in 3 VALU ops
DEV u32 pack2(float a, float b) {
    union { float f; u32 u; } x, y; x.f = a; y.f = b;
    return __builtin_amdgcn_perm(y.u + 0x8000u, x.u + 0x8000u, 0x07060302u);
}

// pack 8 f32 (two float4) -> 8 bf16 (int4)
DEV int4 packA(float4 lo, float4 hi) {
    int4 r;
    r.x = pack2(lo.x, lo.y); r.y = pack2(lo.z, lo.w);
    r.z = pack2(hi.x, hi.y); r.w = pack2(hi.z, hi.w);
    return r;
}

#if __has_builtin(__builtin_amdgcn_exp2f)
DEV float fexp2(float x) { return __builtin_amdgcn_exp2f(x); }
#else
DEV float fexp2(float x) { return __expf(x * 0.69314718056f); }
#endif

DEV f32x4 mfma16(bf16x8 a, bf16x8 b, f32x4 c) {
    return __builtin_amdgcn_mfma_f32_16x16x32_bf16(a, b, c, 0, 0, 0);
}

// ---------------------------------------------------------------------------
// 1) Transpose+convert x[b][c][s] (f32) -> tok[b][s][c] (bf16).  1024 tiles.
// ---------------------------------------------------------------------------
__global__ __launch_bounds__(256) void prep_kernel(const float* __restrict__ x,
                                                   u16* __restrict__ tok) {
    __shared__ u16 t[64][65];
    const int id = blockIdx.x, tid = threadIdx.x;
    const int b = id >> 9, c0 = ((id >> 6) & 7) * 64, s0 = (id & 63) * 64;
    const float* xb = x + ((size_t)b * 512 + c0) * 4096 + s0;
    u16* tb = tok + ((size_t)b * 4096 + s0) * 512 + c0;
    {   // read: 64 rows (c) x 16 float4 cols (s)
        const int jc = tid & 15, i0 = tid >> 4;
#pragma unroll
        for (int ii = 0; ii < 4; ii++) {
            int i = i0 * 4 + ii;
            float4 v = *(const float4*)&xb[(size_t)i * 4096 + jc * 4];
            t[i][jc * 4 + 0] = f2bf(v.x);
            t[i][jc * 4 + 1] = f2bf(v.y);
            t[i][jc * 4 + 2] = f2bf(v.z);
            t[i][jc * 4 + 3] = f2bf(v.w);
        }
    }
    __syncthreads();
    {   // write: 64 rows (s) x 32 u32 cols (c pairs)
        const int j = tid & 31, i0 = tid >> 5;
#pragma unroll
        for (int ii = 0; ii < 8; ii++) {
            int srow = i0 * 8 + ii;
            u32 v = (u32)t[j * 2][srow] | ((u32)t[j * 2 + 1][srow] << 16);
            *(u32*)(&tb[(size_t)srow * 512 + j * 2]) = v;
        }
    }
}

// ---------------------------------------------------------------------------
// 2a) 128x128 projection tile (QKV). Triple-buffered, BK=32, 16 K-steps,
//     one barrier/step, prefetch distance 2 (R8-validated). W is read as F32
//     directly and packed to bf16 at ds_write time (conversion hides in the
//     staging slot).  B (tok) is bf16.
//     mode 0: out bf16 [b][hd][s][d]   mode 1: out bf16 [b*512+co][s]
// ---------------------------------------------------------------------------
DEV void proj128(const float* __restrict__ W, const float* __restrict__ bias,
                 const u16* __restrict__ Bb, void* __restrict__ out,
                 int b, int mode, float scale, int m0, int n0,
                 u16* __restrict__ Ab, u16* __restrict__ Bl) {
    const int tid = threadIdx.x;
    const int wave = tid >> 6, lane = tid & 63, q = lane >> 4, c = lane & 15;

    const int cs = tid & 15, qs = (tid >> 4) & 3, ms = (tid >> 6) & 3;
    const float* Asrc0 = W + (size_t)(m0 + ms * 16 + cs) * 512 + qs * 8;
    const float* Asrc1 = W + (size_t)(m0 + (ms + 4) * 16 + cs) * 512 + qs * 8;
    const u16* Bsrc0 = Bb + (size_t)(n0 + ms * 16 + cs) * 512 + qs * 8;
    const u16* Bsrc1 = Bb + (size_t)(n0 + (ms + 4) * 16 + cs) * 512 + qs * 8;

    f32x4 acc[4][4] = {};

    // prologue: chunk 0 -> buf 0; chunk 1 -> held regs
    {
        float4 a0lo = *(const float4*)&Asrc0[0], a0hi = *(const float4*)&Asrc0[4];
        float4 a1lo = *(const float4*)&Asrc1[0], a1hi = *(const float4*)&Asrc1[4];
        int4 b0 = *(const int4*)&Bsrc0[0];
        int4 b1 = *(const int4*)&Bsrc1[0];
        *(int4*)&Ab[tid * 8]         = packA(a0lo, a0hi);
        *(int4*)&Ab[(tid + 256) * 8] = packA(a1lo, a1hi);
        *(int4*)&Bl[tid * 8]         = b0;
        *(int4*)&Bl[(tid + 256) * 8] = b1;
    }
    float4 h0lo = *(const float4*)&Asrc0[32], h0hi = *(const float4*)&Asrc0[36];
    float4 h1lo = *(const float4*)&Asrc1[32], h1hi = *(const float4*)&Asrc1[36];
    int4 hb0 = *(const int4*)&Bsrc0[32];
    int4 hb1 = *(const int4*)&Bsrc1[32];
    __syncthreads();

    int p = 0, pw = 1;
    for (int it = 0; it < 16; it++) {
        const int kn = ((it + 2) & 15) * 32;   // chunk to prefetch (wraps)

        // (1) issue loads for chunk it+2
        float4 na0lo = *(const float4*)&Asrc0[kn], na0hi = *(const float4*)&Asrc0[kn + 4];
        float4 na1lo = *(const float4*)&Asrc1[kn], na1hi = *(const float4*)&Asrc1[kn + 4];
        int4 nb0 = *(const int4*)&Bsrc0[kn];
        int4 nb1 = *(const int4*)&Bsrc1[kn];

        // (2) compute on buffer p (chunk it)
        bf16x8 af[4], bfr[4];
#pragma unroll
        for (int t = 0; t < 4; t++) {
            int gm = (((wave & 1) * 4 + t) * 4 + q) * 16 + c;
            af[t] = *(const bf16x8*)&Ab[p * 4096 + gm * 8];
            int gn = (((wave >> 1) * 4 + t) * 4 + q) * 16 + c;
            bfr[t] = *(const bf16x8*)&Bl[p * 4096 + gn * 8];
        }
#pragma unroll
        for (int mt = 0; mt < 4; mt++)
#pragma unroll
            for (int nt = 0; nt < 4; nt++)
                acc[mt][nt] = mfma16(af[mt], bfr[nt], acc[mt][nt]);

        // (3) pack+write held chunk it+1 into buffer pw; (4) one barrier
        *(int4*)&Ab[pw * 4096 + tid * 8]         = packA(h0lo, h0hi);
        *(int4*)&Ab[pw * 4096 + (tid + 256) * 8] = packA(h1lo, h1hi);
        *(int4*)&Bl[pw * 4096 + tid * 8]         = hb0;
        *(int4*)&Bl[pw * 4096 + (tid + 256) * 8] = hb1;
        h0lo = na0lo; h0hi = na0hi; h1lo = na1lo; h1hi = na1hi;
        hb0 = nb0; hb1 = nb1;
        __syncthreads();
        p = pw; pw = (pw == 2) ? 0 : pw + 1;
    }

    // epilogue (R2-validated): co = mbase+mt*16+q*4+reg ; s = nbase+nt*16+c
    const int mbase = m0 + (wave & 1) * 64, nbase = n0 + (wave >> 1) * 64;
#pragma unroll
    for (int mt = 0; mt < 4; mt++) {
        int co0 = mbase + mt * 16 + q * 4;
        float b0 = bias[co0 + 0], b1 = bias[co0 + 1];
        float b2 = bias[co0 + 2], b3 = bias[co0 + 3];
#pragma unroll
        for (int nt = 0; nt < 4; nt++) {
            int scol = nbase + nt * 16 + c;
            float v0 = (acc[mt][nt][0] + b0) * scale;
            float v1 = (acc[mt][nt][1] + b1) * scale;
            float v2 = (acc[mt][nt][2] + b2) * scale;
            float v3 = (acc[mt][nt][3] + b3) * scale;
            if (mode == 0) {
                uint2 pv; pv.x = pack2(v0, v1); pv.y = pack2(v2, v3);
                size_t idx = ((size_t)(b * 8 + (co0 >> 6)) * 4096 + scol) * 64 + (co0 & 63);
                *(uint2*)&((u16*)out)[idx] = pv;
            } else {
                u16* o = (u16*)out;
                o[((size_t)(b * 512 + co0 + 0)) * 4096 + scol] = f2bf(v0);
                o[((size_t)(b * 512 + co0 + 1)) * 4096 + scol] = f2bf(v1);
                o[((size_t)(b * 512 + co0 + 2)) * 4096 + scol] = f2bf(v2);
                o[((size_t)(b * 512 + co0 + 3)) * 4096 + scol] = f2bf(v3);
            }
        }
    }
}

__global__ __launch_bounds__(256) void qkv_kernel(
    const float* __restrict__ Wq, const float* __restrict__ bq,
    const float* __restrict__ Wk, const float* __restrict__ bk,
    const float* __restrict__ Wv, const float* __restrict__ bv,
    const u16* __restrict__ tok,
    u16* __restrict__ Qb, u16* __restrict__ Kb, u16* __restrict__ Vb) {
    __shared__ __align__(16) u16 Alds[3 * 4096];   // 24 KB
    __shared__ __align__(16) u16 Blds[3 * 4096];   // 24 KB
    const int z = blockIdx.z, j = z >> 1, b = z & 1;
    const float* W = (j == 0) ? Wq : (j == 1) ? Wk : Wv;
    const float* bias = (j == 0) ? bq : (j == 1) ? bk : bv;
    void* out = (j == 0) ? (void*)Qb : (j == 1) ? (void*)Kb : (void*)Vb;
    const float scale = (j == 0) ? 0.1803368801f : 1.0f;   // log2(e)/8
    const int mode = (j == 2) ? 1 : 0;
    proj128(W, bias, tok + (size_t)b * (4096 * 512), out, b, mode, scale,
            blockIdx.y * 128, blockIdx.x * 128, Alds, Blds);
}

// ---------------------------------------------------------------------------
// 2b) 64x128 projection tile (output projection) — same pipeline, smaller
//     M-tile for 2x grid (512 WGs). f32 output [b][co][s] = [B][C][H][W].
// ---------------------------------------------------------------------------
__global__ __launch_bounds__(256) void projp_kernel(const float* __restrict__ Wp,
                                                    const float* __restrict__ bp,
                                                    const u16* __restrict__ attin,
                                                    float* __restrict__ out) {
    __shared__ __align__(16) u16 Ab[3 * 2048];     // 12 KB
    __shared__ __align__(16) u16 Bl[3 * 4096];     // 24 KB
    const int tid = threadIdx.x;
    const int wave = tid >> 6, lane = tid & 63, q = lane >> 4, c = lane & 15;
    const int m0 = blockIdx.y * 64, n0 = blockIdx.x * 128, b = blockIdx.z;
    const u16* Bb = attin + (size_t)b * (4096 * 512);

    // A: 256 granules (64 rows x 32 k); B: 512 granules (128 rows x 32 k)
    const int cs = tid & 15, qs = (tid >> 4) & 3, ms = (tid >> 6) & 3;
    const float* Asrc = Wp + (size_t)(m0 + ms * 16 + cs) * 512 + qs * 8;
    const u16* Bsrc0 = Bb + (size_t)(n0 + ms * 16 + cs) * 512 + qs * 8;
    const u16* Bsrc1 = Bb + (size_t)(n0 + (ms + 4) * 16 + cs) * 512 + qs * 8;

    f32x4 acc[4][2] = {};

    {
        float4 alo = *(const float4*)&Asrc[0], ahi = *(const float4*)&Asrc[4];
        int4 b0 = *(const int4*)&Bsrc0[0];
        int4 b1 = *(const int4*)&Bsrc1[0];
        *(int4*)&Ab[tid * 8] = packA(alo, ahi);
        *(int4*)&Bl[tid * 8]         = b0;
        *(int4*)&Bl[(tid + 256) * 8] = b1;
    }
    float4 hlo = *(const float4*)&Asrc[32], hhi = *(const float4*)&Asrc[36];
    int4 hb0 = *(const int4*)&Bsrc0[32];
    int4 hb1 = *(const int4*)&Bsrc1[32];
    __syncthreads();

    int p = 0, pw = 1;
    for (int it = 0; it < 16; it++) {
        const int kn = ((it + 2) & 15) * 32;

        float4 nlo = *(const float4*)&Asrc[kn], nhi = *(const float4*)&Asrc[kn + 4];
        int4 nb0 = *(const int4*)&Bsrc0[kn];
        int4 nb1 = *(const int4*)&Bsrc1[kn];

        bf16x8 af[4], bfr[2];
#pragma unroll
        for (int mt = 0; mt < 4; mt++)
            af[mt] = *(const bf16x8*)&Ab[p * 2048 + ((mt * 4 + q) * 16 + c) * 8];
#pragma unroll
        for (int nt = 0; nt < 2; nt++)
            bfr[nt] = *(const bf16x8*)&Bl[p * 4096 + (((wave * 2 + nt) * 4 + q) * 16 + c) * 8];
#pragma unroll
        for (int mt = 0; mt < 4; mt++)
#pragma unroll
            for (int nt = 0; nt < 2; nt++)
                acc[mt][nt] = mfma16(af[mt], bfr[nt], acc[mt][nt]);

        *(int4*)&Ab[pw * 2048 + tid * 8] = packA(hlo, hhi);
        *(int4*)&Bl[pw * 4096 + tid * 8]         = hb0;
        *(int4*)&Bl[pw * 4096 + (tid + 256) * 8] = hb1;
        hlo = nlo; hhi = nhi; hb0 = nb0; hb1 = nb1;
        __syncthreads();
        p = pw; pw = (pw == 2) ? 0 : pw + 1;
    }

    // epilogue (R3-validated 64-tile mapping): co = m0+mt*16+q*4+reg
#pragma unroll
    for (int mt = 0; mt < 4; mt++) {
        int co0 = m0 + mt * 16 + q * 4;
        float b0 = bp[co0 + 0], b1 = bp[co0 + 1];
        float b2 = bp[co0 + 2], b3 = bp[co0 + 3];
#pragma unroll
        for (int nt = 0; nt < 2; nt++) {
            int scol = n0 + wave * 32 + nt * 16 + c;
            out[((size_t)(b * 512 + co0 + 0)) * 4096 + scol] = acc[mt][nt][0] + b0;
            out[((size_t)(b * 512 + co0 + 1)) * 4096 + scol] = acc[mt][nt][1] + b1;
            out[((size_t)(b * 512 + co0 + 2)) * 4096 + scol] = acc[mt][nt][2] + b2;
            out[((size_t)(b * 512 + co0 + 3)) * 4096 + scol] = acc[mt][nt][3] + b3;
        }
    }
}

// ---------------------------------------------------------------------------
// 3) Flash attention (R6/R8 validated, verbatim): fixed-base softmax,
//    double-buffered K/V, one barrier per t-tile, intra-wave P^T shuffle.
// ---------------------------------------------------------------------------
__global__ __launch_bounds__(256) void attn_kernel(const u16* __restrict__ Qm,
                                                   const u16* __restrict__ Km,
                                                   const u16* __restrict__ Vm,
                                                   u16* __restrict__ attout) {
    __shared__ u16 Klds[2][4096];     // 2 x 8KB, frag order (t4,kk,qq,r)
    __shared__ u16 Vlds[2][4096];     // 2 x 8KB, frag order (t4,kk,qq,r)
    __shared__ u16 Plds[128 * 72];    // [s_local][72] padded, 18KB (16B rows)
    const int tid = threadIdx.x, wave = tid >> 6, lane = tid & 63;
    const int q = lane >> 4, c = lane & 15;
    const int bhd = blockIdx.y, s0 = blockIdx.x * 128;
    const u16* Qb = Qm + (size_t)bhd * (4096 * 64);
    const u16* Kb = Km + (size_t)bhd * (4096 * 64);
    const u16* Vb = Vm + (size_t)bhd * (64 * 4096);

    bf16x8 qf[2][2];
#pragma unroll
    for (int st = 0; st < 2; st++)
#pragma unroll
        for (int kd = 0; kd < 2; kd++)
            qf[st][kd] = *(const bf16x8*)
                &Qb[(size_t)(s0 + wave * 32 + st * 16 + c) * 64 + kd * 32 + q * 8];

    const int rr = tid & 15, qq = (tid >> 4) & 3, kk = (tid >> 6) & 1;
    const int t40 = tid >> 7, t41 = t40 + 2;
    const u16* Ksrc0 = Kb + (size_t)(t40 * 16 + rr) * 64 + kk * 32 + qq * 8;
    const u16* Ksrc1 = Kb + (size_t)(t41 * 16 + rr) * 64 + kk * 32 + qq * 8;
    const u16* Vsrc0 = Vb + (size_t)(t40 * 16 + rr) * 4096 + kk * 32 + qq * 8;
    const u16* Vsrc1 = Vb + (size_t)(t41 * 16 + rr) * 4096 + kk * 32 + qq * 8;
    u16* Prow = &Plds[(size_t)(wave * 32 + c) * 72];

    f32x4 oacc[4][2] = {};
    float lsum[2] = {0.f, 0.f};

    *(int4*)&Klds[0][tid * 8]         = *(const int4*)&Ksrc0[0];
    *(int4*)&Klds[0][(tid + 256) * 8] = *(const int4*)&Ksrc1[0];
    *(int4*)&Vlds[0][tid * 8]         = *(const int4*)&Vsrc0[0];
    *(int4*)&Vlds[0][(tid + 256) * 8] = *(const int4*)&Vsrc1[0];
    __syncthreads();

    for (int it = 0; it < 64; it++) {
        const int p = it & 1;
        const size_t t0n = (size_t)(((it + 1) & 63) * 64);

        int4 kst0 = *(const int4*)&Ksrc0[t0n * 64];
        int4 kst1 = *(const int4*)&Ksrc1[t0n * 64];
        int4 vst0 = *(const int4*)&Vsrc0[t0n];
        int4 vst1 = *(const int4*)&Vsrc1[t0n];

        f32x4 sacc[4][2] = {};
#pragma unroll
        for (int kd = 0; kd < 2; kd++) {
            bf16x8 ka[4];
#pragma unroll
            for (int tt = 0; tt < 4; tt++)
                ka[tt] = *(const bf16x8*)&Klds[p][(((tt * 2 + kd) * 4 + q) * 16 + c) * 8];
#pragma unroll
            for (int tt = 0; tt < 4; tt++)
#pragma unroll
                for (int st = 0; st < 2; st++)
                    sacc[tt][st] = mfma16(ka[tt], qf[st][kd], sacc[tt][st]);
        }

#pragma unroll
        for (int st = 0; st < 2; st++) {
#pragma unroll
            for (int tt = 0; tt < 4; tt++) {
                float p0 = fexp2(sacc[tt][st][0]);
                float p1 = fexp2(sacc[tt][st][1]);
                float p2 = fexp2(sacc[tt][st][2]);
                float p3 = fexp2(sacc[tt][st][3]);
                lsum[st] += (p0 + p1) + (p2 + p3);
                uint2 pv; pv.x = pack2(p0, p1); pv.y = pack2(p2, p3);
                *(uint2*)&Prow[st * (16 * 72) + tt * 16 + q * 4] = pv;
            }
        }

#pragma unroll
        for (int kt = 0; kt < 2; kt++) {
            bf16x8 va[4], pb[2];
#pragma unroll
            for (int dt = 0; dt < 4; dt++)
                va[dt] = *(const bf16x8*)&Vlds[p][(((dt * 2 + kt) * 4 + q) * 16 + c) * 8];
#pragma unroll
            for (int st = 0; st < 2; st++)
                pb[st] = *(const bf16x8*)&Prow[st * (16 * 72) + kt * 32 + q * 8];
#pragma unroll
            for (int dt = 0; dt < 4; dt++)
#pragma unroll
                for (int st = 0; st < 2; st++)
                    oacc[dt][st] = mfma16(va[dt], pb[st], oacc[dt][st]);
        }

        *(int4*)&Klds[1 - p][tid * 8]         = kst0;
        *(int4*)&Klds[1 - p][(tid + 256) * 8] = kst1;
        *(int4*)&Vlds[1 - p][tid * 8]         = vst0;
        *(int4*)&Vlds[1 - p][(tid + 256) * 8] = vst1;
        __syncthreads();
    }

    const int b = bhd >> 3, hd = bhd & 7;
#pragma unroll
    for (int st = 0; st < 2; st++) {
        float l = lsum[st];
        l += __shfl_xor(l, 16, 64);
        l += __shfl_xor(l, 32, 64);
        float rl = 1.0f / l;
        int s = s0 + wave * 32 + st * 16 + c;
#pragma unroll
        for (int dt = 0; dt < 4; dt++) {
            uint2 pv;
            pv.x = pack2(oacc[dt][st][0] * rl, oacc[dt][st][1] * rl);
            pv.y = pack2(oacc[dt][st][2] * rl, oacc[dt][st][3] * rl);
            size_t idx = ((size_t)(b * 4096 + s)) * 512 + hd * 64 + dt * 16 + q * 4;
            *(uint2*)&attout[idx] = pv;
        }
    }
}

// ---------------------------------------------------------------------------
extern "C" void kernel_launch(void* const* d_in, const int* in_sizes, int n_in,
                              void* d_out, int out_size, void* d_ws, size_t ws_size,
                              hipStream_t stream) {
    (void)in_sizes; (void)n_in; (void)out_size; (void)ws_size;
    const float* x  = (const float*)d_in[0];
    const float* Wq = (const float*)d_in[1];
    const float* bq = (const float*)d_in[2];
    const float* Wk = (const float*)d_in[3];
    const float* bk = (const float*)d_in[4];
    const float* Wv = (const float*)d_in[5];
    const float* bv = (const float*)d_in[6];
    const float* Wp = (const float*)d_in[7];
    const float* bp = (const float*)d_in[8];
    float* out = (float*)d_out;

    const size_t NTOK = (size_t)4 * 1024 * 1024;  // 2*4096*512 elements
    u16* tok = (u16*)d_ws;        // [2][4096][512] bf16; reused as attout later
    u16* Qb  = tok + NTOK;        // [16][4096][64]  (pre-scaled by log2e/8)
    u16* Kb  = Qb + NTOK;         // [16][4096][64]
    u16* Vb  = Kb + NTOK;         // [16][64][4096]
    u16* attout = tok;            // alias: tok dead after V projection

    prep_kernel<<<dim3(1024), 256, 0, stream>>>(x, tok);
    qkv_kernel<<<dim3(32, 4, 6), 256, 0, stream>>>(Wq, bq, Wk, bk, Wv, bv, tok, Qb, Kb, Vb);
    attn_kernel<<<dim3(32, 16), 256, 0, stream>>>(Qb, Kb, Vb, attout);
    projp_kernel<<<dim3(32, 8, 2), 256, 0, stream>>>(Wp, bp, attout, out);
}

// Round 11
// 225.265 us; speedup vs baseline: 1.8919x; 1.1059x over previous
//
#include <hip/hip_runtime.h>
#include <stdint.h>
#include <math.h>

typedef unsigned short u16;
typedef uint32_t u32;
typedef short bf16x8 __attribute__((ext_vector_type(8)));   // 8 bf16 = 4 VGPRs
typedef float f32x4  __attribute__((ext_vector_type(4)));

#define DEV __device__ __forceinline__

DEV u16 f2bf(float f) {
    union { float f; u32 u; } x; x.f = f;
    u32 lsb = (x.u >> 16) & 1u;
    x.u += 0x7fffu + lsb;            // RNE
    return (u16)(x.u >> 16);
}

// pack two f32 -> two bf16 (round-half-up) in 3 VALU ops
DEV u32 pack2(float a, float b) {
    union { float f; u32 u; } x, y; x.f = a; y.f = b;
    return __builtin_amdgcn_perm(y.u + 0x8000u, x.u + 0x8000u, 0x07060302u);
}

#if __has_builtin(__builtin_amdgcn_exp2f)
DEV float fexp2(float x) { return __builtin_amdgcn_exp2f(x); }
#else
DEV float fexp2(float x) { return __expf(x * 0.69314718056f); }
#endif

DEV f32x4 mfma16(bf16x8 a, bf16x8 b, f32x4 c) {
    return __builtin_amdgcn_mfma_f32_16x16x32_bf16(a, b, c, 0, 0, 0);
}

// ---------------------------------------------------------------------------
// 0) prep: fused (a) transpose+convert x[b][c][s] f32 -> tok[b][s][c] bf16
//          (b) convert 4 f32 weight matrices -> bf16 dst[j][co][ci]
//    blocks 0..1023: transpose tiles; blocks 1024..2047: weight convert.
// ---------------------------------------------------------------------------
__global__ __launch_bounds__(256) void prep_kernel(const float* __restrict__ x,
                                                   u16* __restrict__ tok,
                                                   const float* __restrict__ w0,
                                                   const float* __restrict__ w1,
                                                   const float* __restrict__ w2,
                                                   const float* __restrict__ w3,
                                                   u16* __restrict__ dst) {
    __shared__ u16 t[64][65];
    const int id = blockIdx.x, tid = threadIdx.x;
    if (id < 1024) {
        const int b = id >> 9, c0 = ((id >> 6) & 7) * 64, s0 = (id & 63) * 64;
        const float* xb = x + ((size_t)b * 512 + c0) * 4096 + s0;
        u16* tb = tok + ((size_t)b * 4096 + s0) * 512 + c0;
        {   // read: 64 rows (c) x 16 float4 cols (s)
            const int jc = tid & 15, i0 = tid >> 4;
#pragma unroll
            for (int ii = 0; ii < 4; ii++) {
                int i = i0 * 4 + ii;
                float4 v = *(const float4*)&xb[(size_t)i * 4096 + jc * 4];
                t[i][jc * 4 + 0] = f2bf(v.x);
                t[i][jc * 4 + 1] = f2bf(v.y);
                t[i][jc * 4 + 2] = f2bf(v.z);
                t[i][jc * 4 + 3] = f2bf(v.w);
            }
        }
        __syncthreads();
        {   // write: 64 rows (s) x 32 u32 cols (c pairs)
            const int j = tid & 31, i0 = tid >> 5;
#pragma unroll
            for (int ii = 0; ii < 8; ii++) {
                int srow = i0 * 8 + ii;
                u32 v = (u32)t[j * 2][srow] | ((u32)t[j * 2 + 1][srow] << 16);
                *(u32*)(&tb[(size_t)srow * 512 + j * 2]) = v;
            }
        }
    } else {
        const int id2 = id - 1024;
        const int j = id2 >> 8;
        const float* src = (j == 0) ? w0 : (j == 1) ? w1 : (j == 2) ? w2 : w3;
        int idx = ((id2 & 255) * 256 + tid) * 4;
        float4 v = *(const float4*)&src[idx];
        uint2 pv;
        pv.x = pack2(v.x, v.y);
        pv.y = pack2(v.z, v.w);
        *(uint2*)&dst[(size_t)j * 262144 + idx] = pv;
    }
}

// ---------------------------------------------------------------------------
// 2) Projection GEMM core, TRIPLE-BUFFERED, prefetch distance 2 (R8): 128x128
//    tile, BK=32, 16 K-steps, ONE barrier per step.
//    LDS frag order: granule g: c=g&15, q=(g>>4)&3, mt=g>>6 -> 16B of row
//    mt*16+c, k q*8. 4 waves: wave owns (wave&1) m-half x (wave>>1) n-half.
//    mode 0: out bf16 [b][hd][s][d]   mode 1: out bf16 [b*512+co][s]
//    mode 2: out f32  [b*512+co][s]
// ---------------------------------------------------------------------------
DEV void proj_core(const u16* __restrict__ W, const float* __restrict__ bias,
                   const u16* __restrict__ Bb, void* __restrict__ out,
                   int b, int mode, float scale,
                   u16 (*__restrict__ Alds)[4096], u16 (*__restrict__ Blds)[4096]) {
    const int tid = threadIdx.x;
    const int wave = tid >> 6, lane = tid & 63, q = lane >> 4, c = lane & 15;
    const int m0 = blockIdx.y * 128, n0 = blockIdx.x * 128;

    const int cs = tid & 15, qs = (tid >> 4) & 3, ms = (tid >> 6) & 3;
    const u16* Asrc0 = W  + (size_t)(m0 + ms * 16 + cs) * 512 + qs * 8;
    const u16* Asrc1 = W  + (size_t)(m0 + (ms + 4) * 16 + cs) * 512 + qs * 8;
    const u16* Bsrc0 = Bb + (size_t)(n0 + ms * 16 + cs) * 512 + qs * 8;
    const u16* Bsrc1 = Bb + (size_t)(n0 + (ms + 4) * 16 + cs) * 512 + qs * 8;

    f32x4 acc[4][4] = {};

    // prologue: chunk 0 -> LDS buf 0; chunk 1 held in registers
    int4 pa0 = *(const int4*)&Asrc0[0];
    int4 pa1 = *(const int4*)&Asrc1[0];
    int4 pb0 = *(const int4*)&Bsrc0[0];
    int4 pb1 = *(const int4*)&Bsrc1[0];
    int4 ha0 = *(const int4*)&Asrc0[32];
    int4 ha1 = *(const int4*)&Asrc1[32];
    int4 hb0 = *(const int4*)&Bsrc0[32];
    int4 hb1 = *(const int4*)&Bsrc1[32];
    *(int4*)&Alds[0][tid * 8]         = pa0;
    *(int4*)&Alds[0][(tid + 256) * 8] = pa1;
    *(int4*)&Blds[0][tid * 8]         = pb0;
    *(int4*)&Blds[0][(tid + 256) * 8] = pb1;
    __syncthreads();

    int p = 0, pw = 1;
    for (int it = 0; it < 16; it++) {
        const int kn = ((it + 2) & 15) * 32;   // chunk to prefetch (wraps; harmless)

        // (1) issue loads for chunk it+2 (consumed at iteration it+1's write)
        int4 na0 = *(const int4*)&Asrc0[kn];
        int4 na1 = *(const int4*)&Asrc1[kn];
        int4 nb0 = *(const int4*)&Bsrc0[kn];
        int4 nb1 = *(const int4*)&Bsrc1[kn];

        // (2) compute on buffer p (holds chunk it)
        bf16x8 af[4], bfr[4];
#pragma unroll
        for (int t = 0; t < 4; t++) {
            int gm = (((wave & 1) * 4 + t) * 4 + q) * 16 + c;
            af[t] = *(const bf16x8*)&Alds[p][gm * 8];
            int gn = (((wave >> 1) * 4 + t) * 4 + q) * 16 + c;
            bfr[t] = *(const bf16x8*)&Blds[p][gn * 8];
        }
#pragma unroll
        for (int mt = 0; mt < 4; mt++)
#pragma unroll
            for (int nt = 0; nt < 4; nt++)
                acc[mt][nt] = mfma16(af[mt], bfr[nt], acc[mt][nt]);

        // (3) write held chunk it+1 (loaded one iter ago) into buffer pw
        *(int4*)&Alds[pw][tid * 8]         = ha0;
        *(int4*)&Alds[pw][(tid + 256) * 8] = ha1;
        *(int4*)&Blds[pw][tid * 8]         = hb0;
        *(int4*)&Blds[pw][(tid + 256) * 8] = hb1;
        ha0 = na0; ha1 = na1; hb0 = nb0; hb1 = nb1;
        __syncthreads();
        p = pw; pw = (pw == 2) ? 0 : pw + 1;
    }

    // epilogue (validated R2): co = mbase+mt*16+q*4+reg ; s = nbase+nt*16+c
    const int mbase = m0 + (wave & 1) * 64, nbase = n0 + (wave >> 1) * 64;
#pragma unroll
    for (int mt = 0; mt < 4; mt++) {
        int co0 = mbase + mt * 16 + q * 4;
        float b0 = bias[co0 + 0], b1 = bias[co0 + 1];
        float b2 = bias[co0 + 2], b3 = bias[co0 + 3];
#pragma unroll
        for (int nt = 0; nt < 4; nt++) {
            int scol = nbase + nt * 16 + c;
            float v0 = (acc[mt][nt][0] + b0) * scale;
            float v1 = (acc[mt][nt][1] + b1) * scale;
            float v2 = (acc[mt][nt][2] + b2) * scale;
            float v3 = (acc[mt][nt][3] + b3) * scale;
            if (mode == 0) {
                uint2 pv; pv.x = pack2(v0, v1); pv.y = pack2(v2, v3);
                size_t idx = ((size_t)(b * 8 + (co0 >> 6)) * 4096 + scol) * 64 + (co0 & 63);
                *(uint2*)&((u16*)out)[idx] = pv;
            } else if (mode == 1) {
                u16* o = (u16*)out;
                o[((size_t)(b * 512 + co0 + 0)) * 4096 + scol] = f2bf(v0);
                o[((size_t)(b * 512 + co0 + 1)) * 4096 + scol] = f2bf(v1);
                o[((size_t)(b * 512 + co0 + 2)) * 4096 + scol] = f2bf(v2);
                o[((size_t)(b * 512 + co0 + 3)) * 4096 + scol] = f2bf(v3);
            } else {
                float* o = (float*)out;
                o[((size_t)(b * 512 + co0 + 0)) * 4096 + scol] = v0;
                o[((size_t)(b * 512 + co0 + 1)) * 4096 + scol] = v1;
                o[((size_t)(b * 512 + co0 + 2)) * 4096 + scol] = v2;
                o[((size_t)(b * 512 + co0 + 3)) * 4096 + scol] = v3;
            }
        }
    }
}

// fused Q/K/V projection: blockIdx.z in [0,6): j = z>>1 (0=Q,1=K,2=V), b = z&1
// Q is pre-scaled by log2(e)/8 so attention scores are in the exp2 domain.
__global__ __launch_bounds__(256) void qkv_kernel(const u16* __restrict__ Wbf,
                                                  const float* __restrict__ bq,
                                                  const float* __restrict__ bk,
                                                  const float* __restrict__ bv,
                                                  const u16* __restrict__ tok,
                                                  u16* __restrict__ Qb,
                                                  u16* __restrict__ Kb,
                                                  u16* __restrict__ Vb) {
    __shared__ u16 Alds[3][4096];    // 3 x 8KB
    __shared__ u16 Blds[3][4096];    // 3 x 8KB
    const int z = blockIdx.z, j = z >> 1, b = z & 1;
    const u16* W = Wbf + (size_t)j * 262144;
    const float* bias = (j == 0) ? bq : (j == 1) ? bk : bv;
    void* out = (j == 0) ? (void*)Qb : (j == 1) ? (void*)Kb : (void*)Vb;
    const float scale = (j == 0) ? 0.1803368801f : 1.0f;   // log2(e)/8
    const int mode = (j == 2) ? 1 : 0;
    proj_core(W, bias, tok + (size_t)b * (4096 * 512), out, b, mode, scale, Alds, Blds);
}

// final projection: blockIdx.z = batch, f32 output
__global__ __launch_bounds__(256) void projp_kernel(const u16* __restrict__ Wp,
                                                    const float* __restrict__ bp,
                                                    const u16* __restrict__ attout,
                                                    float* __restrict__ out) {
    __shared__ u16 Alds[3][4096];
    __shared__ u16 Blds[3][4096];
    const int b = blockIdx.z;
    proj_core(Wp, bp, attout + (size_t)b * (4096 * 512), out, b, 2, 1.0f, Alds, Blds);
}

// ---------------------------------------------------------------------------
// 3) Flash attention (R6/R8 structure, verbatim) with XCD-locality grid:
//    blockIdx.x = bhd (16), blockIdx.y = s-block (32). Flat id = sblk*16+bhd,
//    so id mod 8 = bhd mod 8 -> all 32 WGs of a head land on one XCD
//    (2 heads/XCD, K+V = 2MB resident in the 4MB per-XCD L2).
//    Fixed-base softmax, double-buffered K/V, one barrier per t-tile,
//    intra-wave P^T shuffle.
// ---------------------------------------------------------------------------
__global__ __launch_bounds__(256) void attn_kernel(const u16* __restrict__ Qm,
                                                   const u16* __restrict__ Km,
                                                   const u16* __restrict__ Vm,
                                                   u16* __restrict__ attout) {
    __shared__ u16 Klds[2][4096];     // 2 x 8KB, frag order (t4,kk,qq,r)
    __shared__ u16 Vlds[2][4096];     // 2 x 8KB, frag order (t4,kk,qq,r)
    __shared__ u16 Plds[128 * 72];    // [s_local][72] padded, 18KB (16B rows)
    const int tid = threadIdx.x, wave = tid >> 6, lane = tid & 63;
    const int q = lane >> 4, c = lane & 15;
    const int bhd = blockIdx.x, s0 = blockIdx.y * 128;   // XCD-locality swizzle
    const u16* Qb = Qm + (size_t)bhd * (4096 * 64);
    const u16* Kb = Km + (size_t)bhd * (4096 * 64);
    const u16* Vb = Vm + (size_t)bhd * (64 * 4096);

    bf16x8 qf[2][2];
#pragma unroll
    for (int st = 0; st < 2; st++)
#pragma unroll
        for (int kd = 0; kd < 2; kd++)
            qf[st][kd] = *(const bf16x8*)
                &Qb[(size_t)(s0 + wave * 32 + st * 16 + c) * 64 + kd * 32 + q * 8];

    const int rr = tid & 15, qq = (tid >> 4) & 3, kk = (tid >> 6) & 1;
    const int t40 = tid >> 7, t41 = t40 + 2;
    const u16* Ksrc0 = Kb + (size_t)(t40 * 16 + rr) * 64 + kk * 32 + qq * 8;
    const u16* Ksrc1 = Kb + (size_t)(t41 * 16 + rr) * 64 + kk * 32 + qq * 8;
    const u16* Vsrc0 = Vb + (size_t)(t40 * 16 + rr) * 4096 + kk * 32 + qq * 8;
    const u16* Vsrc1 = Vb + (size_t)(t41 * 16 + rr) * 4096 + kk * 32 + qq * 8;
    u16* Prow = &Plds[(size_t)(wave * 32 + c) * 72];

    f32x4 oacc[4][2] = {};
    float lsum[2] = {0.f, 0.f};

    *(int4*)&Klds[0][tid * 8]         = *(const int4*)&Ksrc0[0];
    *(int4*)&Klds[0][(tid + 256) * 8] = *(const int4*)&Ksrc1[0];
    *(int4*)&Vlds[0][tid * 8]         = *(const int4*)&Vsrc0[0];
    *(int4*)&Vlds[0][(tid + 256) * 8] = *(const int4*)&Vsrc1[0];
    __syncthreads();

    for (int it = 0; it < 64; it++) {
        const int p = it & 1;
        const size_t t0n = (size_t)(((it + 1) & 63) * 64);

        int4 kst0 = *(const int4*)&Ksrc0[t0n * 64];
        int4 kst1 = *(const int4*)&Ksrc1[t0n * 64];
        int4 vst0 = *(const int4*)&Vsrc0[t0n];
        int4 vst1 = *(const int4*)&Vsrc1[t0n];

        f32x4 sacc[4][2] = {};
#pragma unroll
        for (int kd = 0; kd < 2; kd++) {
            bf16x8 ka[4];
#pragma unroll
            for (int tt = 0; tt < 4; tt++)
                ka[tt] = *(const bf16x8*)&Klds[p][(((tt * 2 + kd) * 4 + q) * 16 + c) * 8];
#pragma unroll
            for (int tt = 0; tt < 4; tt++)
#pragma unroll
                for (int st = 0; st < 2; st++)
                    sacc[tt][st] = mfma16(ka[tt], qf[st][kd], sacc[tt][st]);
        }

#pragma unroll
        for (int st = 0; st < 2; st++) {
#pragma unroll
            for (int tt = 0; tt < 4; tt++) {
                float p0 = fexp2(sacc[tt][st][0]);
                float p1 = fexp2(sacc[tt][st][1]);
                float p2 = fexp2(sacc[tt][st][2]);
                float p3 = fexp2(sacc[tt][st][3]);
                lsum[st] += (p0 + p1) + (p2 + p3);
                uint2 pv; pv.x = pack2(p0, p1); pv.y = pack2(p2, p3);
                *(uint2*)&Prow[st * (16 * 72) + tt * 16 + q * 4] = pv;
            }
        }

#pragma unroll
        for (int kt = 0; kt < 2; kt++) {
            bf16x8 va[4], pb[2];
#pragma unroll
            for (int dt = 0; dt < 4; dt++)
                va[dt] = *(const bf16x8*)&Vlds[p][(((dt * 2 + kt) * 4 + q) * 16 + c) * 8];
#pragma unroll
            for (int st = 0; st < 2; st++)
                pb[st] = *(const bf16x8*)&Prow[st * (16 * 72) + kt * 32 + q * 8];
#pragma unroll
            for (int dt = 0; dt < 4; dt++)
#pragma unroll
                for (int st = 0; st < 2; st++)
                    oacc[dt][st] = mfma16(va[dt], pb[st], oacc[dt][st]);
        }

        *(int4*)&Klds[1 - p][tid * 8]         = kst0;
        *(int4*)&Klds[1 - p][(tid + 256) * 8] = kst1;
        *(int4*)&Vlds[1 - p][tid * 8]         = vst0;
        *(int4*)&Vlds[1 - p][(tid + 256) * 8] = vst1;
        __syncthreads();
    }

    const int b = bhd >> 3, hd = bhd & 7;
#pragma unroll
    for (int st = 0; st < 2; st++) {
        float l = lsum[st];
        l += __shfl_xor(l, 16, 64);
        l += __shfl_xor(l, 32, 64);
        float rl = 1.0f / l;
        int s = s0 + wave * 32 + st * 16 + c;
#pragma unroll
        for (int dt = 0; dt < 4; dt++) {
            uint2 pv;
            pv.x = pack2(oacc[dt][st][0] * rl, oacc[dt][st][1] * rl);
            pv.y = pack2(oacc[dt][st][2] * rl, oacc[dt][st][3] * rl);
            size_t idx = ((size_t)(b * 4096 + s)) * 512 + hd * 64 + dt * 16 + q * 4;
            *(uint2*)&attout[idx] = pv;
        }
    }
}

// ---------------------------------------------------------------------------
extern "C" void kernel_launch(void* const* d_in, const int* in_sizes, int n_in,
                              void* d_out, int out_size, void* d_ws, size_t ws_size,
                              hipStream_t stream) {
    (void)in_sizes; (void)n_in; (void)out_size; (void)ws_size;
    const float* x  = (const float*)d_in[0];
    const float* Wq = (const float*)d_in[1];
    const float* bq = (const float*)d_in[2];
    const float* Wk = (const float*)d_in[3];
    const float* bk = (const float*)d_in[4];
    const float* Wv = (const float*)d_in[5];
    const float* bv = (const float*)d_in[6];
    const float* Wp = (const float*)d_in[7];
    const float* bp = (const float*)d_in[8];
    float* out = (float*)d_out;

    const size_t NTOK = (size_t)4 * 1024 * 1024;  // 2*4096*512 elements
    u16* tok = (u16*)d_ws;        // [2][4096][512] bf16; reused as attout later
    u16* Qb  = tok + NTOK;        // [16][4096][64]  (pre-scaled by log2e/8)
    u16* Kb  = Qb + NTOK;         // [16][4096][64]
    u16* Vb  = Kb + NTOK;         // [16][64][4096]
    u16* Wbf = Vb + NTOK;         // [4][512][512] bf16 (q,k,v,p)
    u16* attout = tok;            // alias: tok dead after V projection

    prep_kernel<<<dim3(2048), 256, 0, stream>>>(x, tok, Wq, Wk, Wv, Wp, Wbf);
    qkv_kernel<<<dim3(32, 4, 6), 256, 0, stream>>>(Wbf, bq, bk, bv, tok, Qb, Kb, Vb);
    attn_kernel<<<dim3(16, 32), 256, 0, stream>>>(Qb, Kb, Vb, attout);
    projp_kernel<<<dim3(32, 4, 2), 256, 0, stream>>>(Wbf + 3 * 262144, bp, attout, out);
}